// Round 5
// baseline (431.393 us; speedup 1.0000x reference)
//
#include <hip/hip_runtime.h>
#include <hip/hip_bf16.h>

#define DM 1024
#define BS 4
#define SS 1024
#define NH 16

typedef __attribute__((ext_vector_type(8))) short bf16x8;
typedef __attribute__((ext_vector_type(4))) float f32x4;

__device__ inline unsigned short f2bf(float x) {
    union { float f; unsigned u; } v; v.f = x;
    unsigned r = v.u + 0x7fffu + ((v.u >> 16) & 1u);
    return (unsigned short)(r >> 16);
}

template<typename T> __device__ inline void fetch4(const T* p, unsigned short* d);
template<> __device__ inline void fetch4<float>(const float* p, unsigned short* d) {
    float4 v = *reinterpret_cast<const float4*>(p);
    d[0] = f2bf(v.x); d[1] = f2bf(v.y); d[2] = f2bf(v.z); d[3] = f2bf(v.w);
}
template<> __device__ inline void fetch4<unsigned short>(const unsigned short* p, unsigned short* d) {
    *reinterpret_cast<uint2*>(d) = *reinterpret_cast<const uint2*>(p);
}

template<typename T> __device__ inline void store1(T* p, float v);
template<> __device__ inline void store1<float>(float* p, float v) { *p = v; }
template<> __device__ inline void store1<unsigned short>(unsigned short* p, float v) { *p = f2bf(v); }

// C[M,N] = scale * (A[M,K] @ B[N,K]^T) + bias[N]   (round-1 verified)
template<int BM, int BN, int WR, int WC, typename TA, typename TB, typename TO>
__global__ __launch_bounds__(256) void gemm_abt(
    const TA* __restrict__ A, int lda, long long sAb, long long sAh,
    const TB* __restrict__ B, int ldb, long long sBb, long long sBh,
    TO* __restrict__ C, int ldc, long long sCb, long long sCh,
    const float* __restrict__ bias, int K, int H, float scale)
{
    constexpr int LDK = 40;
    constexpr int MF = BM / WR / 16;
    constexpr int NF = BN / WC / 16;
    __shared__ unsigned short lA[BM * LDK];
    __shared__ unsigned short lB[BN * LDK];

    const int tid = threadIdx.x;
    const int z = blockIdx.z;
    const int zb = z / H, zh = z % H;
    const TA* Ap = A + sAb * zb + sAh * zh + (long long)blockIdx.y * BM * lda;
    const TB* Bp = B + sBb * zb + sBh * zh + (long long)blockIdx.x * BN * ldb;
    TO* Cp = C + sCb * zb + sCh * zh + (long long)blockIdx.y * BM * ldc + (long long)blockIdx.x * BN;

    const int wid = tid >> 6, lane = tid & 63;
    const int wr = wid / WC, wc = wid % WC;
    const int r0 = lane & 15;
    const int kq = (lane >> 4) * 8;

    f32x4 acc[MF][NF];
    #pragma unroll
    for (int m = 0; m < MF; ++m)
        #pragma unroll
        for (int n = 0; n < NF; ++n)
            acc[m][n] = f32x4{0.f, 0.f, 0.f, 0.f};

    for (int kt = 0; kt < K; kt += 32) {
        __syncthreads();
        #pragma unroll
        for (int qi = 0; qi < BM * 8 / 256; ++qi) {
            int idx = tid + qi * 256;
            int row = idx >> 3, c4 = idx & 7;
            unsigned short tmp[4];
            fetch4<TA>(Ap + (long long)row * lda + kt + c4 * 4, tmp);
            *reinterpret_cast<uint2*>(&lA[row * LDK + c4 * 4]) = *reinterpret_cast<const uint2*>(tmp);
        }
        #pragma unroll
        for (int qi = 0; qi < BN * 8 / 256; ++qi) {
            int idx = tid + qi * 256;
            int row = idx >> 3, c4 = idx & 7;
            unsigned short tmp[4];
            fetch4<TB>(Bp + (long long)row * ldb + kt + c4 * 4, tmp);
            *reinterpret_cast<uint2*>(&lB[row * LDK + c4 * 4]) = *reinterpret_cast<const uint2*>(tmp);
        }
        __syncthreads();

        bf16x8 af[MF], bfr[NF];
        #pragma unroll
        for (int m = 0; m < MF; ++m)
            af[m] = *reinterpret_cast<const bf16x8*>(&lA[(wr * MF * 16 + m * 16 + r0) * LDK + kq]);
        #pragma unroll
        for (int n = 0; n < NF; ++n)
            bfr[n] = *reinterpret_cast<const bf16x8*>(&lB[(wc * NF * 16 + n * 16 + r0) * LDK + kq]);
        #pragma unroll
        for (int m = 0; m < MF; ++m)
            #pragma unroll
            for (int n = 0; n < NF; ++n)
                acc[m][n] = __builtin_amdgcn_mfma_f32_16x16x32_bf16(af[m], bfr[n], acc[m][n], 0, 0, 0);
    }

    const int cf = lane & 15, rf = (lane >> 4) * 4;
    #pragma unroll
    for (int m = 0; m < MF; ++m) {
        #pragma unroll
        for (int n = 0; n < NF; ++n) {
            int col = wc * NF * 16 + n * 16 + cf;
            float bv = bias ? bias[blockIdx.x * BN + col] : 0.0f;
            #pragma unroll
            for (int j = 0; j < 4; ++j) {
                int row = wr * MF * 16 + m * 16 + rf + j;
                store1<TO>(&Cp[(long long)row * ldc + col], acc[m][n][j] * scale + bv);
            }
        }
    }
}

// vT[(b*NH+h)*64 + d][t] = v_p[b][t][h*64+d]   (round-1 verified)
__global__ __launch_bounds__(256) void transpose_vh(const unsigned short* __restrict__ vp,
                                                    unsigned short* __restrict__ vT)
{
    __shared__ unsigned short tile[64][65];
    const int bh = blockIdx.y;
    const int b = bh >> 4, h = bh & 15;
    const long long t0 = (long long)blockIdx.x * 64;
    const int tid = threadIdx.x;
    #pragma unroll
    for (int kk = 0; kk < 4; ++kk) {
        int l = tid + kk * 256;
        int row = l >> 4, c4 = l & 15;
        const unsigned short* src = vp + ((long long)b * SS + t0 + row) * DM + h * 64 + c4 * 4;
        ushort4 val = *reinterpret_cast<const ushort4*>(src);
        tile[row][c4 * 4 + 0] = val.x;
        tile[row][c4 * 4 + 1] = val.y;
        tile[row][c4 * 4 + 2] = val.z;
        tile[row][c4 * 4 + 3] = val.w;
    }
    __syncthreads();
    #pragma unroll
    for (int kk = 0; kk < 4; ++kk) {
        int l = tid + kk * 256;
        int d = l >> 4, i4 = l & 15;
        ushort4 o;
        o.x = tile[i4 * 4 + 0][d];
        o.y = tile[i4 * 4 + 1][d];
        o.z = tile[i4 * 4 + 2][d];
        o.w = tile[i4 * 4 + 3][d];
        *reinterpret_cast<ushort4*>(vT + ((long long)bh * 64 + d) * SS + t0 + i4 * 4) = o;
    }
}

// Kernel A: S strip (bf16 LDS) + exact two-pass softmax stats from registers + PV -> cc.
// Writes stats[z*SS+row] = (rowMax, 1/rowSum). No attnw traffic.
// Grid: (SS/16, B*NH), 256 threads = 4 waves.
__global__ __launch_bounds__(256) void attn_pv(
    const unsigned short* __restrict__ qp,   // [B,S,DM] bf16
    const unsigned short* __restrict__ kp,   // [B,S,DM] bf16
    const unsigned short* __restrict__ vT,   // [B*NH*64, S] bf16
    float2* __restrict__ stats,              // [B*NH, S] (m, inv)
    unsigned short* __restrict__ cc)         // [B,S,DM] bf16
{
    constexpr int LSTR = 1032;               // bf16 stride (2064 B)
    __shared__ alignas(16) unsigned short S16[16 * LSTR];   // 33 KB
    __shared__ float mW[4][16];
    __shared__ float sW[4][16];
    __shared__ float rowMax[16];

    const int tid = threadIdx.x;
    const int w = tid >> 6;
    const int lane = tid & 63;
    const int lg = lane >> 4;
    const int ln = lane & 15;
    const int z = blockIdx.y, b = z >> 4, h = z & 15;
    const int row0 = blockIdx.x * 16;

    const unsigned short* qbase = qp + ((long long)b * SS + row0) * DM + h * 64;
    const unsigned short* kbase = kp + (long long)b * SS * DM + h * 64;
    const unsigned short* vbase = vT + (long long)z * 64 * SS;

    bf16x8 qf[2];
    #pragma unroll
    for (int ks = 0; ks < 2; ++ks)
        qf[ks] = *reinterpret_cast<const bf16x8*>(qbase + (long long)ln * DM + ks * 32 + lg * 8);

    // ---- Phase 1: S strip (scaled) -> bf16 LDS; keep all S values in regs ----
    float sreg[8][2][4];                     // [c][cf][j], statically indexed
    #pragma unroll
    for (int c = 0; c < 8; ++c) {
        const int colbase = c * 128 + w * 32;
        f32x4 sac[2];
        sac[0] = f32x4{0.f, 0.f, 0.f, 0.f};
        sac[1] = f32x4{0.f, 0.f, 0.f, 0.f};
        #pragma unroll
        for (int ks = 0; ks < 2; ++ks) {
            #pragma unroll
            for (int cf2 = 0; cf2 < 2; ++cf2) {
                bf16x8 kf = *reinterpret_cast<const bf16x8*>(
                    kbase + (long long)(colbase + cf2 * 16 + ln) * DM + ks * 32 + lg * 8);
                sac[cf2] = __builtin_amdgcn_mfma_f32_16x16x32_bf16(qf[ks], kf, sac[cf2], 0, 0, 0);
            }
        }
        #pragma unroll
        for (int cf2 = 0; cf2 < 2; ++cf2)
            #pragma unroll
            for (int j = 0; j < 4; ++j) {
                float s = sac[cf2][j] * 0.125f;
                sreg[c][cf2][j] = s;
                S16[(lg * 4 + j) * LSTR + colbase + cf2 * 16 + ln] = f2bf(s);
            }
    }

    // ---- exact two-pass stats from registers ----
    float m4[4];
    #pragma unroll
    for (int j = 0; j < 4; ++j) {
        float mx = sreg[0][0][j];
        #pragma unroll
        for (int c = 0; c < 8; ++c)
            #pragma unroll
            for (int cf2 = 0; cf2 < 2; ++cf2)
                mx = fmaxf(mx, sreg[c][cf2][j]);
        #pragma unroll
        for (int o = 1; o < 16; o <<= 1) mx = fmaxf(mx, __shfl_xor(mx, o));
        m4[j] = mx;
    }
    if (ln == 0) {
        #pragma unroll
        for (int j = 0; j < 4; ++j) mW[w][lg * 4 + j] = m4[j];
    }
    __syncthreads();
    if (tid < 16)
        rowMax[tid] = fmaxf(fmaxf(mW[0][tid], mW[1][tid]), fmaxf(mW[2][tid], mW[3][tid]));
    __syncthreads();
    float s4[4];
    #pragma unroll
    for (int j = 0; j < 4; ++j) {
        float mf = rowMax[lg * 4 + j];
        float se = 0.f;
        #pragma unroll
        for (int c = 0; c < 8; ++c)
            #pragma unroll
            for (int cf2 = 0; cf2 < 2; ++cf2)
                se += __expf(sreg[c][cf2][j] - mf);
        #pragma unroll
        for (int o = 1; o < 16; o <<= 1) se += __shfl_xor(se, o);
        s4[j] = se;
    }
    if (ln == 0) {
        #pragma unroll
        for (int j = 0; j < 4; ++j) sW[w][lg * 4 + j] = s4[j];
    }
    __syncthreads();
    if (tid < 16) {
        float se = sW[0][tid] + sW[1][tid] + sW[2][tid] + sW[3][tid];
        stats[(long long)z * SS + row0 + tid] = make_float2(rowMax[tid], 1.0f / se);
    }

    // ---- Phase 2b: PV, wave w owns d in [w*16, w*16+16)  (round-4 verified) ----
    {
        f32x4 pvn = f32x4{0.f, 0.f, 0.f, 0.f};
        const unsigned short* vrow = vbase + (long long)(w * 16 + ln) * SS;
        for (int kk = 0; kk < 32; ++kk) {
            bf16x8 sa = *reinterpret_cast<const bf16x8*>(&S16[ln * LSTR + kk * 32 + lg * 8]);
            bf16x8 vf = *reinterpret_cast<const bf16x8*>(vrow + kk * 32 + lg * 8);
            pvn = __builtin_amdgcn_mfma_f32_16x16x32_bf16(sa, vf, pvn, 0, 0, 0);
        }
        #pragma unroll
        for (int j = 0; j < 4; ++j)
            cc[((long long)b * SS + row0 + lg * 4 + j) * DM + h * 64 + w * 16 + ln] = f2bf(pvn[j]);
    }
}

// Kernel B: recompute S (bitwise-identical MFMA sequence), apply exp(S-m)*inv, stream attnw.
// LDS bounce for coalesced 512B row-segment stores. Grid: (SS/16, B*NH), 256 threads.
__global__ __launch_bounds__(256) void softmax_write(
    const unsigned short* __restrict__ qp,
    const unsigned short* __restrict__ kp,
    const float2* __restrict__ stats,
    float* __restrict__ attnw)
{
    __shared__ alignas(16) float T[16][136];   // 8.5 KB bounce
    const int tid = threadIdx.x;
    const int w = tid >> 6;
    const int lane = tid & 63;
    const int lg = lane >> 4;
    const int ln = lane & 15;
    const int z = blockIdx.y, b = z >> 4, h = z & 15;
    const int row0 = blockIdx.x * 16;

    const unsigned short* qbase = qp + ((long long)b * SS + row0) * DM + h * 64;
    const unsigned short* kbase = kp + (long long)b * SS * DM + h * 64;

    bf16x8 qf[2];
    #pragma unroll
    for (int ks = 0; ks < 2; ++ks)
        qf[ks] = *reinterpret_cast<const bf16x8*>(qbase + (long long)ln * DM + ks * 32 + lg * 8);

    float2 st[4];
    #pragma unroll
    for (int j = 0; j < 4; ++j)
        st[j] = stats[(long long)z * SS + row0 + lg * 4 + j];

    const int rr = tid >> 4, c0 = (tid & 15) * 8;
    float* orow = attnw + ((long long)z * SS + row0 + rr) * SS;

    for (int c = 0; c < 8; ++c) {
        const int colbase = w * 32;
        f32x4 sac[2];
        sac[0] = f32x4{0.f, 0.f, 0.f, 0.f};
        sac[1] = f32x4{0.f, 0.f, 0.f, 0.f};
        #pragma unroll
        for (int ks = 0; ks < 2; ++ks) {
            #pragma unroll
            for (int cf2 = 0; cf2 < 2; ++cf2) {
                bf16x8 kf = *reinterpret_cast<const bf16x8*>(
                    kbase + (long long)(c * 128 + colbase + cf2 * 16 + ln) * DM + ks * 32 + lg * 8);
                sac[cf2] = __builtin_amdgcn_mfma_f32_16x16x32_bf16(qf[ks], kf, sac[cf2], 0, 0, 0);
            }
        }
        #pragma unroll
        for (int cf2 = 0; cf2 < 2; ++cf2)
            #pragma unroll
            for (int j = 0; j < 4; ++j)
                T[lg * 4 + j][colbase + cf2 * 16 + ln] =
                    __expf(sac[cf2][j] * 0.125f - st[j].x) * st[j].y;
        __syncthreads();
        float4 w0 = *reinterpret_cast<const float4*>(&T[rr][c0]);
        float4 w1 = *reinterpret_cast<const float4*>(&T[rr][c0 + 4]);
        *reinterpret_cast<float4*>(orow + c * 128 + c0) = w0;
        *reinterpret_cast<float4*>(orow + c * 128 + c0 + 4) = w1;
        __syncthreads();
    }
}

extern "C" void kernel_launch(void* const* d_in, const int* in_sizes, int n_in,
                              void* d_out, int out_size, void* d_ws, size_t ws_size,
                              hipStream_t stream) {
    (void)in_sizes; (void)n_in; (void)out_size; (void)ws_size;
    const float* v    = (const float*)d_in[0];
    const float* q    = (const float*)d_in[2];
    const float* wq_w = (const float*)d_in[3];
    const float* wq_b = (const float*)d_in[4];
    const float* wv_w = (const float*)d_in[5];
    const float* wv_b = (const float*)d_in[6];
    const float* dw   = (const float*)d_in[7];
    const float* db   = (const float*)d_in[8];

    unsigned short* q_p = (unsigned short*)d_ws;
    unsigned short* v_p = q_p + (4 << 20);
    unsigned short* k_p = v_p + (4 << 20);
    unsigned short* vT  = k_p + (4 << 20);
    unsigned short* cc  = vT  + (4 << 20);
    float2* stats = (float2*)(cc + (4 << 20));   // 512 KB

    float* out0   = (float*)d_out;
    float* attnw  = out0 + (long long)BS * SS * DM;

    dim3 blk(256);

    gemm_abt<128,128,2,2,float,float,unsigned short><<<dim3(8,32,1),blk,0,stream>>>(
        q, DM, 0, 0, wq_w, DM, 0, 0, q_p, DM, 0, 0, wq_b, DM, 1, 1.0f);
    gemm_abt<128,128,2,2,float,float,unsigned short><<<dim3(8,32,1),blk,0,stream>>>(
        v, DM, 0, 0, wv_w, DM, 0, 0, v_p, DM, 0, 0, wv_b, DM, 1, 1.0f);
    gemm_abt<128,128,2,2,unsigned short,float,unsigned short><<<dim3(8,32,1),blk,0,stream>>>(
        v_p, DM, 0, 0, wv_w, DM, 0, 0, k_p, DM, 0, 0, wv_b, DM, 1, 1.0f);
    transpose_vh<<<dim3(16,64),blk,0,stream>>>(v_p, vT);

    attn_pv<<<dim3(SS/16, BS*NH), blk, 0, stream>>>(q_p, k_p, vT, stats, cc);

    gemm_abt<128,128,2,2,unsigned short,float,float><<<dim3(8,32,1),blk,0,stream>>>(
        cc, DM, 0, 0, dw, DM, 0, 0, out0, DM, 0, 0, db, DM, 1, 1.0f);

    softmax_write<<<dim3(SS/16, BS*NH), blk, 0, stream>>>(q_p, k_p, stats, attnw);
}

// Round 6
// 361.844 us; speedup vs baseline: 1.1922x; 1.1922x over previous
//
#include <hip/hip_runtime.h>
#include <hip/hip_bf16.h>

#define DM 1024
#define BS 4
#define SS 1024
#define NH 16

typedef __attribute__((ext_vector_type(8))) short bf16x8;
typedef __attribute__((ext_vector_type(4))) float f32x4;

__device__ inline unsigned short f2bf(float x) {
    union { float f; unsigned u; } v; v.f = x;
    unsigned r = v.u + 0x7fffu + ((v.u >> 16) & 1u);
    return (unsigned short)(r >> 16);
}

template<typename T> __device__ inline void fetch4(const T* p, unsigned short* d);
template<> __device__ inline void fetch4<float>(const float* p, unsigned short* d) {
    float4 v = *reinterpret_cast<const float4*>(p);
    d[0] = f2bf(v.x); d[1] = f2bf(v.y); d[2] = f2bf(v.z); d[3] = f2bf(v.w);
}
template<> __device__ inline void fetch4<unsigned short>(const unsigned short* p, unsigned short* d) {
    *reinterpret_cast<uint2*>(d) = *reinterpret_cast<const uint2*>(p);
}

template<typename T> __device__ inline void store1(T* p, float v);
template<> __device__ inline void store1<float>(float* p, float v) { *p = v; }
template<> __device__ inline void store1<unsigned short>(unsigned short* p, float v) { *p = f2bf(v); }

// C[M,N] = scale * (A[M,K] @ B[N,K]^T) + bias[N]   (round-1 verified)
template<int BM, int BN, int WR, int WC, typename TA, typename TB, typename TO>
__global__ __launch_bounds__(256) void gemm_abt(
    const TA* __restrict__ A, int lda, long long sAb, long long sAh,
    const TB* __restrict__ B, int ldb, long long sBb, long long sBh,
    TO* __restrict__ C, int ldc, long long sCb, long long sCh,
    const float* __restrict__ bias, int K, int H, float scale)
{
    constexpr int LDK = 40;
    constexpr int MF = BM / WR / 16;
    constexpr int NF = BN / WC / 16;
    __shared__ unsigned short lA[BM * LDK];
    __shared__ unsigned short lB[BN * LDK];

    const int tid = threadIdx.x;
    const int z = blockIdx.z;
    const int zb = z / H, zh = z % H;
    const TA* Ap = A + sAb * zb + sAh * zh + (long long)blockIdx.y * BM * lda;
    const TB* Bp = B + sBb * zb + sBh * zh + (long long)blockIdx.x * BN * ldb;
    TO* Cp = C + sCb * zb + sCh * zh + (long long)blockIdx.y * BM * ldc + (long long)blockIdx.x * BN;

    const int wid = tid >> 6, lane = tid & 63;
    const int wr = wid / WC, wc = wid % WC;
    const int r0 = lane & 15;
    const int kq = (lane >> 4) * 8;

    f32x4 acc[MF][NF];
    #pragma unroll
    for (int m = 0; m < MF; ++m)
        #pragma unroll
        for (int n = 0; n < NF; ++n)
            acc[m][n] = f32x4{0.f, 0.f, 0.f, 0.f};

    for (int kt = 0; kt < K; kt += 32) {
        __syncthreads();
        #pragma unroll
        for (int qi = 0; qi < BM * 8 / 256; ++qi) {
            int idx = tid + qi * 256;
            int row = idx >> 3, c4 = idx & 7;
            unsigned short tmp[4];
            fetch4<TA>(Ap + (long long)row * lda + kt + c4 * 4, tmp);
            *reinterpret_cast<uint2*>(&lA[row * LDK + c4 * 4]) = *reinterpret_cast<const uint2*>(tmp);
        }
        #pragma unroll
        for (int qi = 0; qi < BN * 8 / 256; ++qi) {
            int idx = tid + qi * 256;
            int row = idx >> 3, c4 = idx & 7;
            unsigned short tmp[4];
            fetch4<TB>(Bp + (long long)row * ldb + kt + c4 * 4, tmp);
            *reinterpret_cast<uint2*>(&lB[row * LDK + c4 * 4]) = *reinterpret_cast<const uint2*>(tmp);
        }
        __syncthreads();

        bf16x8 af[MF], bfr[NF];
        #pragma unroll
        for (int m = 0; m < MF; ++m)
            af[m] = *reinterpret_cast<const bf16x8*>(&lA[(wr * MF * 16 + m * 16 + r0) * LDK + kq]);
        #pragma unroll
        for (int n = 0; n < NF; ++n)
            bfr[n] = *reinterpret_cast<const bf16x8*>(&lB[(wc * NF * 16 + n * 16 + r0) * LDK + kq]);
        #pragma unroll
        for (int m = 0; m < MF; ++m)
            #pragma unroll
            for (int n = 0; n < NF; ++n)
                acc[m][n] = __builtin_amdgcn_mfma_f32_16x16x32_bf16(af[m], bfr[n], acc[m][n], 0, 0, 0);
    }

    const int cf = lane & 15, rf = (lane >> 4) * 4;
    #pragma unroll
    for (int m = 0; m < MF; ++m) {
        #pragma unroll
        for (int n = 0; n < NF; ++n) {
            int col = wc * NF * 16 + n * 16 + cf;
            float bv = bias ? bias[blockIdx.x * BN + col] : 0.0f;
            #pragma unroll
            for (int j = 0; j < 4; ++j) {
                int row = wr * MF * 16 + m * 16 + rf + j;
                store1<TO>(&Cp[(long long)row * ldc + col], acc[m][n][j] * scale + bv);
            }
        }
    }
}

// vT[(b*NH+h)*64 + d][t] = v_p[b][t][h*64+d]   (round-1 verified)
__global__ __launch_bounds__(256) void transpose_vh(const unsigned short* __restrict__ vp,
                                                    unsigned short* __restrict__ vT)
{
    __shared__ unsigned short tile[64][65];
    const int bh = blockIdx.y;
    const int b = bh >> 4, h = bh & 15;
    const long long t0 = (long long)blockIdx.x * 64;
    const int tid = threadIdx.x;
    #pragma unroll
    for (int kk = 0; kk < 4; ++kk) {
        int l = tid + kk * 256;
        int row = l >> 4, c4 = l & 15;
        const unsigned short* src = vp + ((long long)b * SS + t0 + row) * DM + h * 64 + c4 * 4;
        ushort4 val = *reinterpret_cast<const ushort4*>(src);
        tile[row][c4 * 4 + 0] = val.x;
        tile[row][c4 * 4 + 1] = val.y;
        tile[row][c4 * 4 + 2] = val.z;
        tile[row][c4 * 4 + 3] = val.w;
    }
    __syncthreads();
    #pragma unroll
    for (int kk = 0; kk < 4; ++kk) {
        int l = tid + kk * 256;
        int d = l >> 4, i4 = l & 15;
        ushort4 o;
        o.x = tile[i4 * 4 + 0][d];
        o.y = tile[i4 * 4 + 1][d];
        o.z = tile[i4 * 4 + 2][d];
        o.w = tile[i4 * 4 + 3][d];
        *reinterpret_cast<ushort4*>(vT + ((long long)bh * 64 + d) * SS + t0 + i4 * 4) = o;
    }
}

// Fused attention v2 (merge of round-4/5 verified pieces):
//   P1: QK^T -> sreg f32 (regs) + S16 bf16 LDS          [round-5 verified]
//   P2: exact two-pass stats from registers -> LDS      [round-5 verified]
//   P3: attnw = exp(sreg - m) * inv, direct reg stores  [new; same arithmetic]
//   P4: PV from S16 -> cc                               [round-4/5 verified]
// Grid: (SS/16, B*NH), 256 threads = 4 waves.
__global__ __launch_bounds__(256) void fused_attn2(
    const unsigned short* __restrict__ qp,   // [B,S,DM] bf16
    const unsigned short* __restrict__ kp,   // [B,S,DM] bf16
    const unsigned short* __restrict__ vT,   // [B*NH*64, S] bf16
    float* __restrict__ attnw,               // [B,NH,S,S] f32
    unsigned short* __restrict__ cc)         // [B,S,DM] bf16
{
    constexpr int LSTR = 1032;               // bf16 stride (2064 B)
    __shared__ alignas(16) unsigned short S16[16 * LSTR];   // 33 KB
    __shared__ float mW[4][16];
    __shared__ float sW[4][16];
    __shared__ float rowMax[16];
    __shared__ float rowInv[16];

    const int tid = threadIdx.x;
    const int w = tid >> 6;
    const int lane = tid & 63;
    const int lg = lane >> 4;
    const int ln = lane & 15;
    const int z = blockIdx.y, b = z >> 4, h = z & 15;
    const int row0 = blockIdx.x * 16;

    const unsigned short* qbase = qp + ((long long)b * SS + row0) * DM + h * 64;
    const unsigned short* kbase = kp + (long long)b * SS * DM + h * 64;
    const unsigned short* vbase = vT + (long long)z * 64 * SS;

    bf16x8 qf[2];
    #pragma unroll
    for (int ks = 0; ks < 2; ++ks)
        qf[ks] = *reinterpret_cast<const bf16x8*>(qbase + (long long)ln * DM + ks * 32 + lg * 8);

    // ---- Phase 1: S strip -> sreg (f32) + S16 (bf16 LDS) ----
    float sreg[8][2][4];                     // [c][cf][j], statically indexed
    #pragma unroll
    for (int c = 0; c < 8; ++c) {
        const int colbase = c * 128 + w * 32;
        f32x4 sac[2];
        sac[0] = f32x4{0.f, 0.f, 0.f, 0.f};
        sac[1] = f32x4{0.f, 0.f, 0.f, 0.f};
        #pragma unroll
        for (int ks = 0; ks < 2; ++ks) {
            #pragma unroll
            for (int cf2 = 0; cf2 < 2; ++cf2) {
                bf16x8 kf = *reinterpret_cast<const bf16x8*>(
                    kbase + (long long)(colbase + cf2 * 16 + ln) * DM + ks * 32 + lg * 8);
                sac[cf2] = __builtin_amdgcn_mfma_f32_16x16x32_bf16(qf[ks], kf, sac[cf2], 0, 0, 0);
            }
        }
        #pragma unroll
        for (int cf2 = 0; cf2 < 2; ++cf2)
            #pragma unroll
            for (int j = 0; j < 4; ++j) {
                float s = sac[cf2][j] * 0.125f;
                sreg[c][cf2][j] = s;
                S16[(lg * 4 + j) * LSTR + colbase + cf2 * 16 + ln] = f2bf(s);
            }
    }

    // ---- Phase 2: exact two-pass stats from registers ----
    float m4[4];
    #pragma unroll
    for (int j = 0; j < 4; ++j) {
        float mx = sreg[0][0][j];
        #pragma unroll
        for (int c = 0; c < 8; ++c)
            #pragma unroll
            for (int cf2 = 0; cf2 < 2; ++cf2)
                mx = fmaxf(mx, sreg[c][cf2][j]);
        #pragma unroll
        for (int o = 1; o < 16; o <<= 1) mx = fmaxf(mx, __shfl_xor(mx, o));
        m4[j] = mx;
    }
    if (ln == 0) {
        #pragma unroll
        for (int j = 0; j < 4; ++j) mW[w][lg * 4 + j] = m4[j];
    }
    __syncthreads();
    if (tid < 16)
        rowMax[tid] = fmaxf(fmaxf(mW[0][tid], mW[1][tid]), fmaxf(mW[2][tid], mW[3][tid]));
    __syncthreads();
    float s4[4];
    #pragma unroll
    for (int j = 0; j < 4; ++j) {
        float mf = rowMax[lg * 4 + j];
        float se = 0.f;
        #pragma unroll
        for (int c = 0; c < 8; ++c)
            #pragma unroll
            for (int cf2 = 0; cf2 < 2; ++cf2)
                se += __expf(sreg[c][cf2][j] - mf);
        #pragma unroll
        for (int o = 1; o < 16; o <<= 1) se += __shfl_xor(se, o);
        s4[j] = se;
    }
    if (ln == 0) {
        #pragma unroll
        for (int j = 0; j < 4; ++j) sW[w][lg * 4 + j] = s4[j];
    }
    __syncthreads();
    if (tid < 16)
        rowInv[tid] = 1.0f / (sW[0][tid] + sW[1][tid] + sW[2][tid] + sW[3][tid]);
    __syncthreads();

    // ---- Phase 3: attnw direct stores from registers ----
    // wave-store = 4 rows x 16 consecutive floats = 4 x 64B segments (full lines)
    {
        float mf[4], inv[4];
        #pragma unroll
        for (int j = 0; j < 4; ++j) {
            mf[j] = rowMax[lg * 4 + j];
            inv[j] = rowInv[lg * 4 + j];
        }
        #pragma unroll
        for (int c = 0; c < 8; ++c) {
            const int colbase = c * 128 + w * 32;
            #pragma unroll
            for (int cf2 = 0; cf2 < 2; ++cf2)
                #pragma unroll
                for (int j = 0; j < 4; ++j)
                    attnw[((long long)z * SS + row0 + lg * 4 + j) * SS + colbase + cf2 * 16 + ln] =
                        __expf(sreg[c][cf2][j] - mf[j]) * inv[j];
        }
    }

    // ---- Phase 4: PV, wave w owns d in [w*16, w*16+16)  (round-4/5 verified) ----
    {
        f32x4 pvn = f32x4{0.f, 0.f, 0.f, 0.f};
        const unsigned short* vrow = vbase + (long long)(w * 16 + ln) * SS;
        for (int kk = 0; kk < 32; ++kk) {
            bf16x8 sa = *reinterpret_cast<const bf16x8*>(&S16[ln * LSTR + kk * 32 + lg * 8]);
            bf16x8 vf = *reinterpret_cast<const bf16x8*>(vrow + kk * 32 + lg * 8);
            pvn = __builtin_amdgcn_mfma_f32_16x16x32_bf16(sa, vf, pvn, 0, 0, 0);
        }
        #pragma unroll
        for (int j = 0; j < 4; ++j)
            cc[((long long)b * SS + row0 + lg * 4 + j) * DM + h * 64 + w * 16 + ln] = f2bf(pvn[j]);
    }
}

extern "C" void kernel_launch(void* const* d_in, const int* in_sizes, int n_in,
                              void* d_out, int out_size, void* d_ws, size_t ws_size,
                              hipStream_t stream) {
    (void)in_sizes; (void)n_in; (void)out_size; (void)ws_size;
    const float* v    = (const float*)d_in[0];
    const float* q    = (const float*)d_in[2];
    const float* wq_w = (const float*)d_in[3];
    const float* wq_b = (const float*)d_in[4];
    const float* wv_w = (const float*)d_in[5];
    const float* wv_b = (const float*)d_in[6];
    const float* dw   = (const float*)d_in[7];
    const float* db   = (const float*)d_in[8];

    unsigned short* q_p = (unsigned short*)d_ws;
    unsigned short* v_p = q_p + (4 << 20);
    unsigned short* k_p = v_p + (4 << 20);
    unsigned short* vT  = k_p + (4 << 20);
    unsigned short* cc  = vT  + (4 << 20);

    float* out0   = (float*)d_out;
    float* attnw  = out0 + (long long)BS * SS * DM;

    dim3 blk(256);

    gemm_abt<128,128,2,2,float,float,unsigned short><<<dim3(8,32,1),blk,0,stream>>>(
        q, DM, 0, 0, wq_w, DM, 0, 0, q_p, DM, 0, 0, wq_b, DM, 1, 1.0f);
    gemm_abt<128,128,2,2,float,float,unsigned short><<<dim3(8,32,1),blk,0,stream>>>(
        v, DM, 0, 0, wv_w, DM, 0, 0, v_p, DM, 0, 0, wv_b, DM, 1, 1.0f);
    gemm_abt<128,128,2,2,unsigned short,float,unsigned short><<<dim3(8,32,1),blk,0,stream>>>(
        v_p, DM, 0, 0, wv_w, DM, 0, 0, k_p, DM, 0, 0, wv_b, DM, 1, 1.0f);
    transpose_vh<<<dim3(16,64),blk,0,stream>>>(v_p, vT);

    fused_attn2<<<dim3(SS/16, BS*NH), blk, 0, stream>>>(q_p, k_p, vT, attnw, cc);

    gemm_abt<128,128,2,2,unsigned short,float,float><<<dim3(8,32,1),blk,0,stream>>>(
        cc, DM, 0, 0, dw, DM, 0, 0, out0, DM, 0, 0, db, DM, 1, 1.0f);
}

// Round 7
// 256.110 us; speedup vs baseline: 1.6844x; 1.4128x over previous
//
#include <hip/hip_runtime.h>
#include <hip/hip_bf16.h>

#define DM 1024
#define BS 4
#define SS 1024
#define NH 16

typedef __attribute__((ext_vector_type(8))) short bf16x8;
typedef __attribute__((ext_vector_type(4))) float f32x4;

__device__ inline unsigned short f2bf(float x) {
    union { float f; unsigned u; } v; v.f = x;
    unsigned r = v.u + 0x7fffu + ((v.u >> 16) & 1u);
    return (unsigned short)(r >> 16);
}

template<typename T> __device__ inline void store1(T* p, float v);
template<> __device__ inline void store1<float>(float* p, float v) { *p = v; }
template<> __device__ inline void store1<unsigned short>(unsigned short* p, float v) { *p = f2bf(v); }

// async global->LDS, 16B per lane; LDS dest = wave-uniform base + lane*16
__device__ inline void glds16(const unsigned short* g, unsigned short* l) {
    __builtin_amdgcn_global_load_lds(
        (const __attribute__((address_space(1))) unsigned int*)g,
        (__attribute__((address_space(3))) unsigned int*)l, 16, 0, 0);
}

// fp32 -> bf16 elementwise, float4/ushort4 vectorized, grid-stride
__global__ __launch_bounds__(256) void cvt_bf16(const float* __restrict__ in,
                                                unsigned short* __restrict__ out, int n4)
{
    int i = blockIdx.x * blockDim.x + threadIdx.x;
    const int stride = gridDim.x * blockDim.x;
    for (; i < n4; i += stride) {
        float4 v = reinterpret_cast<const float4*>(in)[i];
        ushort4 o;
        o.x = f2bf(v.x); o.y = f2bf(v.y); o.z = f2bf(v.z); o.w = f2bf(v.w);
        reinterpret_cast<ushort4*>(out)[i] = o;
    }
}

// C[M,N] = scale*(A[M,K] @ B[N,K]^T) + bias[N], all-bf16 inputs, glds staging.
// 64x64 tile, 4 waves (2x2), BK=32, linear LDS (fragment reads are wave-contiguous 1KB).
// Grid: (N/64, M/64).
template<typename TO>
__global__ __launch_bounds__(256) void gemm64_bt(
    const unsigned short* __restrict__ A, int lda,
    const unsigned short* __restrict__ B, int ldb,
    TO* __restrict__ C, int ldc,
    const float* __restrict__ bias, int K, float scale)
{
    __shared__ unsigned short lA[64 * 32];
    __shared__ unsigned short lB[64 * 32];

    const int tid = threadIdx.x;
    const int wid = tid >> 6, lane = tid & 63;
    const int wr = wid >> 1, wc = wid & 1;
    const int r0 = lane & 15;
    const int kq = (lane >> 4) * 8;
    const int srow = lane >> 2;          // staging: 16 rows per wave-chunk
    const int scol = (lane & 3) * 8;     // 4 lanes x 8 elems = 64B row

    const unsigned short* Ap = A + (long long)blockIdx.y * 64 * lda;
    const unsigned short* Bp = B + (long long)blockIdx.x * 64 * ldb;
    TO* Cp = C + (long long)blockIdx.y * 64 * ldc + blockIdx.x * 64;

    f32x4 acc[2][2];
    #pragma unroll
    for (int m = 0; m < 2; ++m)
        #pragma unroll
        for (int n = 0; n < 2; ++n)
            acc[m][n] = f32x4{0.f, 0.f, 0.f, 0.f};

    for (int kt = 0; kt < K; kt += 32) {
        __syncthreads();
        // wave 'wid' stages rows [16*wid, 16*wid+16) of both tiles
        glds16(Ap + (long long)(wid * 16 + srow) * lda + kt + scol, &lA[wid * 512]);
        glds16(Bp + (long long)(wid * 16 + srow) * ldb + kt + scol, &lB[wid * 512]);
        __syncthreads();

        bf16x8 af[2], bfr[2];
        #pragma unroll
        for (int m = 0; m < 2; ++m)
            af[m] = *reinterpret_cast<const bf16x8*>(&lA[(wr * 32 + m * 16 + r0) * 32 + kq]);
        #pragma unroll
        for (int n = 0; n < 2; ++n)
            bfr[n] = *reinterpret_cast<const bf16x8*>(&lB[(wc * 32 + n * 16 + r0) * 32 + kq]);
        #pragma unroll
        for (int m = 0; m < 2; ++m)
            #pragma unroll
            for (int n = 0; n < 2; ++n)
                acc[m][n] = __builtin_amdgcn_mfma_f32_16x16x32_bf16(af[m], bfr[n], acc[m][n], 0, 0, 0);
    }

    const int cf = lane & 15, rf = (lane >> 4) * 4;
    #pragma unroll
    for (int m = 0; m < 2; ++m) {
        #pragma unroll
        for (int n = 0; n < 2; ++n) {
            int col = wc * 32 + n * 16 + cf;
            float bv = bias ? bias[blockIdx.x * 64 + col] : 0.0f;
            #pragma unroll
            for (int j = 0; j < 4; ++j) {
                int row = wr * 32 + m * 16 + rf + j;
                store1<TO>(&Cp[(long long)row * ldc + col], acc[m][n][j] * scale + bv);
            }
        }
    }
}

// vT[(b*NH+h)*64 + d][t] = v_p[b][t][h*64+d]   (round-1 verified)
__global__ __launch_bounds__(256) void transpose_vh(const unsigned short* __restrict__ vp,
                                                    unsigned short* __restrict__ vT)
{
    __shared__ unsigned short tile[64][65];
    const int bh = blockIdx.y;
    const int b = bh >> 4, h = bh & 15;
    const long long t0 = (long long)blockIdx.x * 64;
    const int tid = threadIdx.x;
    #pragma unroll
    for (int kk = 0; kk < 4; ++kk) {
        int l = tid + kk * 256;
        int row = l >> 4, c4 = l & 15;
        const unsigned short* src = vp + ((long long)b * SS + t0 + row) * DM + h * 64 + c4 * 4;
        ushort4 val = *reinterpret_cast<const ushort4*>(src);
        tile[row][c4 * 4 + 0] = val.x;
        tile[row][c4 * 4 + 1] = val.y;
        tile[row][c4 * 4 + 2] = val.z;
        tile[row][c4 * 4 + 3] = val.w;
    }
    __syncthreads();
    #pragma unroll
    for (int kk = 0; kk < 4; ++kk) {
        int l = tid + kk * 256;
        int d = l >> 4, i4 = l & 15;
        ushort4 o;
        o.x = tile[i4 * 4 + 0][d];
        o.y = tile[i4 * 4 + 1][d];
        o.z = tile[i4 * 4 + 2][d];
        o.w = tile[i4 * 4 + 3][d];
        *reinterpret_cast<ushort4*>(vT + ((long long)bh * 64 + d) * SS + t0 + i4 * 4) = o;
    }
}

// Fused attention v2 (round-6 verified, unchanged):
__global__ __launch_bounds__(256) void fused_attn2(
    const unsigned short* __restrict__ qp,   // [B,S,DM] bf16
    const unsigned short* __restrict__ kp,   // [B,S,DM] bf16
    const unsigned short* __restrict__ vT,   // [B*NH*64, S] bf16
    float* __restrict__ attnw,               // [B,NH,S,S] f32
    unsigned short* __restrict__ cc)         // [B,S,DM] bf16
{
    constexpr int LSTR = 1032;
    __shared__ alignas(16) unsigned short S16[16 * LSTR];   // 33 KB
    __shared__ float mW[4][16];
    __shared__ float sW[4][16];
    __shared__ float rowMax[16];
    __shared__ float rowInv[16];

    const int tid = threadIdx.x;
    const int w = tid >> 6;
    const int lane = tid & 63;
    const int lg = lane >> 4;
    const int ln = lane & 15;
    const int z = blockIdx.y, b = z >> 4, h = z & 15;
    const int row0 = blockIdx.x * 16;

    const unsigned short* qbase = qp + ((long long)b * SS + row0) * DM + h * 64;
    const unsigned short* kbase = kp + (long long)b * SS * DM + h * 64;
    const unsigned short* vbase = vT + (long long)z * 64 * SS;

    bf16x8 qf[2];
    #pragma unroll
    for (int ks = 0; ks < 2; ++ks)
        qf[ks] = *reinterpret_cast<const bf16x8*>(qbase + (long long)ln * DM + ks * 32 + lg * 8);

    float sreg[8][2][4];
    #pragma unroll
    for (int c = 0; c < 8; ++c) {
        const int colbase = c * 128 + w * 32;
        f32x4 sac[2];
        sac[0] = f32x4{0.f, 0.f, 0.f, 0.f};
        sac[1] = f32x4{0.f, 0.f, 0.f, 0.f};
        #pragma unroll
        for (int ks = 0; ks < 2; ++ks) {
            #pragma unroll
            for (int cf2 = 0; cf2 < 2; ++cf2) {
                bf16x8 kf = *reinterpret_cast<const bf16x8*>(
                    kbase + (long long)(colbase + cf2 * 16 + ln) * DM + ks * 32 + lg * 8);
                sac[cf2] = __builtin_amdgcn_mfma_f32_16x16x32_bf16(qf[ks], kf, sac[cf2], 0, 0, 0);
            }
        }
        #pragma unroll
        for (int cf2 = 0; cf2 < 2; ++cf2)
            #pragma unroll
            for (int j = 0; j < 4; ++j) {
                float s = sac[cf2][j] * 0.125f;
                sreg[c][cf2][j] = s;
                S16[(lg * 4 + j) * LSTR + colbase + cf2 * 16 + ln] = f2bf(s);
            }
    }

    float m4[4];
    #pragma unroll
    for (int j = 0; j < 4; ++j) {
        float mx = sreg[0][0][j];
        #pragma unroll
        for (int c = 0; c < 8; ++c)
            #pragma unroll
            for (int cf2 = 0; cf2 < 2; ++cf2)
                mx = fmaxf(mx, sreg[c][cf2][j]);
        #pragma unroll
        for (int o = 1; o < 16; o <<= 1) mx = fmaxf(mx, __shfl_xor(mx, o));
        m4[j] = mx;
    }
    if (ln == 0) {
        #pragma unroll
        for (int j = 0; j < 4; ++j) mW[w][lg * 4 + j] = m4[j];
    }
    __syncthreads();
    if (tid < 16)
        rowMax[tid] = fmaxf(fmaxf(mW[0][tid], mW[1][tid]), fmaxf(mW[2][tid], mW[3][tid]));
    __syncthreads();
    float s4[4];
    #pragma unroll
    for (int j = 0; j < 4; ++j) {
        float mf = rowMax[lg * 4 + j];
        float se = 0.f;
        #pragma unroll
        for (int c = 0; c < 8; ++c)
            #pragma unroll
            for (int cf2 = 0; cf2 < 2; ++cf2)
                se += __expf(sreg[c][cf2][j] - mf);
        #pragma unroll
        for (int o = 1; o < 16; o <<= 1) se += __shfl_xor(se, o);
        s4[j] = se;
    }
    if (ln == 0) {
        #pragma unroll
        for (int j = 0; j < 4; ++j) sW[w][lg * 4 + j] = s4[j];
    }
    __syncthreads();
    if (tid < 16)
        rowInv[tid] = 1.0f / (sW[0][tid] + sW[1][tid] + sW[2][tid] + sW[3][tid]);
    __syncthreads();

    {
        float mf[4], inv[4];
        #pragma unroll
        for (int j = 0; j < 4; ++j) {
            mf[j] = rowMax[lg * 4 + j];
            inv[j] = rowInv[lg * 4 + j];
        }
        #pragma unroll
        for (int c = 0; c < 8; ++c) {
            const int colbase = c * 128 + w * 32;
            #pragma unroll
            for (int cf2 = 0; cf2 < 2; ++cf2)
                #pragma unroll
                for (int j = 0; j < 4; ++j)
                    attnw[((long long)z * SS + row0 + lg * 4 + j) * SS + colbase + cf2 * 16 + ln] =
                        __expf(sreg[c][cf2][j] - mf[j]) * inv[j];
        }
    }

    {
        f32x4 pvn = f32x4{0.f, 0.f, 0.f, 0.f};
        const unsigned short* vrow = vbase + (long long)(w * 16 + ln) * SS;
        for (int kk = 0; kk < 32; ++kk) {
            bf16x8 sa = *reinterpret_cast<const bf16x8*>(&S16[ln * LSTR + kk * 32 + lg * 8]);
            bf16x8 vf = *reinterpret_cast<const bf16x8*>(vrow + kk * 32 + lg * 8);
            pvn = __builtin_amdgcn_mfma_f32_16x16x32_bf16(sa, vf, pvn, 0, 0, 0);
        }
        #pragma unroll
        for (int j = 0; j < 4; ++j)
            cc[((long long)b * SS + row0 + lg * 4 + j) * DM + h * 64 + w * 16 + ln] = f2bf(pvn[j]);
    }
}

extern "C" void kernel_launch(void* const* d_in, const int* in_sizes, int n_in,
                              void* d_out, int out_size, void* d_ws, size_t ws_size,
                              hipStream_t stream) {
    (void)in_sizes; (void)n_in; (void)out_size; (void)ws_size;
    const float* v    = (const float*)d_in[0];
    const float* q    = (const float*)d_in[2];
    const float* wq_w = (const float*)d_in[3];
    const float* wq_b = (const float*)d_in[4];
    const float* wv_w = (const float*)d_in[5];
    const float* wv_b = (const float*)d_in[6];
    const float* dw   = (const float*)d_in[7];
    const float* db   = (const float*)d_in[8];

    // workspace: 5 x 4M bf16 = 40 MB
    unsigned short* q_p = (unsigned short*)d_ws;
    unsigned short* v_p = q_p + (4 << 20);
    unsigned short* k_p = v_p + (4 << 20);
    unsigned short* vT  = k_p + (4 << 20);
    unsigned short* cc  = vT  + (4 << 20);

    float* out0   = (float*)d_out;
    float* attnw  = out0 + (long long)BS * SS * DM;

    // bf16 conversion buffers parked in the attnw region (dead until fused_attn2)
    unsigned short* qb  = (unsigned short*)attnw;
    unsigned short* vb  = qb  + (4 << 20);
    unsigned short* wqb = vb  + (4 << 20);
    unsigned short* wvb = wqb + (1 << 20);
    // dwb reuses q_p's slot AFTER fused_attn2 (q_p dead by then)
    unsigned short* dwb = q_p;

    dim3 blk(256);
    dim3 gemmGrid(DM / 64, BS * SS / 64);    // (16, 64)

    cvt_bf16<<<dim3(1024), blk, 0, stream>>>(q, qb, (BS * SS * DM) / 4);
    cvt_bf16<<<dim3(1024), blk, 0, stream>>>(v, vb, (BS * SS * DM) / 4);
    cvt_bf16<<<dim3(256),  blk, 0, stream>>>(wq_w, wqb, (DM * DM) / 4);
    cvt_bf16<<<dim3(256),  blk, 0, stream>>>(wv_w, wvb, (DM * DM) / 4);

    gemm64_bt<unsigned short><<<gemmGrid, blk, 0, stream>>>(
        qb, DM, wqb, DM, q_p, DM, wq_b, DM, 1.0f);
    gemm64_bt<unsigned short><<<gemmGrid, blk, 0, stream>>>(
        vb, DM, wvb, DM, v_p, DM, wv_b, DM, 1.0f);
    gemm64_bt<unsigned short><<<gemmGrid, blk, 0, stream>>>(
        v_p, DM, wvb, DM, k_p, DM, wv_b, DM, 1.0f);

    transpose_vh<<<dim3(16, 64), blk, 0, stream>>>(v_p, vT);

    fused_attn2<<<dim3(SS / 16, BS * NH), blk, 0, stream>>>(q_p, k_p, vT, attnw, cc);

    cvt_bf16<<<dim3(256), blk, 0, stream>>>(dw, dwb, (DM * DM) / 4);
    gemm64_bt<float><<<gemmGrid, blk, 0, stream>>>(
        cc, DM, dwb, DM, out0, DM, db, DM, 1.0f);
}

// Round 8
// 249.297 us; speedup vs baseline: 1.7304x; 1.0273x over previous
//
#include <hip/hip_runtime.h>
#include <hip/hip_bf16.h>

#define DM 1024
#define BS 4
#define SS 1024
#define NH 16

typedef __attribute__((ext_vector_type(8))) short bf16x8;
typedef __attribute__((ext_vector_type(4))) float f32x4;

__device__ inline unsigned short f2bf(float x) {
    union { float f; unsigned u; } v; v.f = x;
    unsigned r = v.u + 0x7fffu + ((v.u >> 16) & 1u);
    return (unsigned short)(r >> 16);
}
__device__ inline float bf2f(unsigned short u) {
    union { unsigned u; float f; } v; v.u = ((unsigned)u) << 16;
    return v.f;
}

template<typename T> __device__ inline void store1(T* p, float v);
template<> __device__ inline void store1<float>(float* p, float v) { *p = v; }
template<> __device__ inline void store1<unsigned short>(unsigned short* p, float v) { *p = f2bf(v); }

// async global->LDS, 16B per lane; LDS dest = wave-uniform base + lane*16
__device__ inline void glds16(const unsigned short* g, unsigned short* l) {
    __builtin_amdgcn_global_load_lds(
        (const __attribute__((address_space(1))) unsigned int*)g,
        (__attribute__((address_space(3))) unsigned int*)l, 16, 0, 0);
}

// fp32 -> bf16 elementwise, float4/ushort4 vectorized, grid-stride
__global__ __launch_bounds__(256) void cvt_bf16(const float* __restrict__ in,
                                                unsigned short* __restrict__ out, int n4)
{
    int i = blockIdx.x * blockDim.x + threadIdx.x;
    const int stride = gridDim.x * blockDim.x;
    for (; i < n4; i += stride) {
        float4 v = reinterpret_cast<const float4*>(in)[i];
        ushort4 o;
        o.x = f2bf(v.x); o.y = f2bf(v.y); o.z = f2bf(v.z); o.w = f2bf(v.w);
        reinterpret_cast<ushort4*>(out)[i] = o;
    }
}

// C[M,N] = scale*(A[M,K] @ B[N,K]^T) + bias[N], all-bf16, glds16 staging,
// 2-phase pipeline (T3 minimum): STAGE(next) -> compute(cur) -> one barrier/iter.
// 64x64 tile, 4 waves (2x2), BK=32. Grid: (N/64, M/64).
template<typename TO>
__global__ __launch_bounds__(256) void gemm64_bt(
    const unsigned short* __restrict__ A, int lda,
    const unsigned short* __restrict__ B, int ldb,
    TO* __restrict__ C, int ldc,
    const float* __restrict__ bias, int K, float scale)
{
    __shared__ unsigned short lA[2][64 * 32];
    __shared__ unsigned short lB[2][64 * 32];

    const int tid = threadIdx.x;
    const int wid = tid >> 6, lane = tid & 63;
    const int wr = wid >> 1, wc = wid & 1;
    const int r0 = lane & 15;
    const int kq = (lane >> 4) * 8;
    const int srow = lane >> 2;          // staging: 16 rows per wave-chunk
    const int scol = (lane & 3) * 8;     // 4 lanes x 8 elems = 64B row

    const unsigned short* Ap = A + ((long long)blockIdx.y * 64 + wid * 16 + srow) * lda + scol;
    const unsigned short* Bp = B + ((long long)blockIdx.x * 64 + wid * 16 + srow) * ldb + scol;
    TO* Cp = C + (long long)blockIdx.y * 64 * ldc + blockIdx.x * 64;

    f32x4 acc[2][2];
    #pragma unroll
    for (int m = 0; m < 2; ++m)
        #pragma unroll
        for (int n = 0; n < 2; ++n)
            acc[m][n] = f32x4{0.f, 0.f, 0.f, 0.f};

    // prologue: stage tile 0
    glds16(Ap, &lA[0][wid * 512]);
    glds16(Bp, &lB[0][wid * 512]);
    __syncthreads();

    const int NT = K / 32;
    int cur = 0;
    for (int t = 0; t < NT; ++t) {
        if (t + 1 < NT) {
            glds16(Ap + (t + 1) * 32, &lA[cur ^ 1][wid * 512]);
            glds16(Bp + (t + 1) * 32, &lB[cur ^ 1][wid * 512]);
        }
        bf16x8 af[2], bfr[2];
        #pragma unroll
        for (int m = 0; m < 2; ++m)
            af[m] = *reinterpret_cast<const bf16x8*>(&lA[cur][(wr * 32 + m * 16 + r0) * 32 + kq]);
        #pragma unroll
        for (int n = 0; n < 2; ++n)
            bfr[n] = *reinterpret_cast<const bf16x8*>(&lB[cur][(wc * 32 + n * 16 + r0) * 32 + kq]);
        #pragma unroll
        for (int m = 0; m < 2; ++m)
            #pragma unroll
            for (int n = 0; n < 2; ++n)
                acc[m][n] = __builtin_amdgcn_mfma_f32_16x16x32_bf16(af[m], bfr[n], acc[m][n], 0, 0, 0);
        __syncthreads();   // drains vmcnt (staged tile landed) + lgkm
        cur ^= 1;
    }

    const int cf = lane & 15, rf = (lane >> 4) * 4;
    #pragma unroll
    for (int m = 0; m < 2; ++m) {
        #pragma unroll
        for (int n = 0; n < 2; ++n) {
            int col = wc * 32 + n * 16 + cf;
            float bv = bias ? bias[blockIdx.x * 64 + col] : 0.0f;
            #pragma unroll
            for (int j = 0; j < 4; ++j) {
                int row = wr * 32 + m * 16 + rf + j;
                store1<TO>(&Cp[(long long)row * ldc + col], acc[m][n][j] * scale + bv);
            }
        }
    }
}

// vT[(b*NH+h)*64 + d][t] = v_p[b][t][h*64+d]   (round-1 verified)
__global__ __launch_bounds__(256) void transpose_vh(const unsigned short* __restrict__ vp,
                                                    unsigned short* __restrict__ vT)
{
    __shared__ unsigned short tile[64][65];
    const int bh = blockIdx.y;
    const int b = bh >> 4, h = bh & 15;
    const long long t0 = (long long)blockIdx.x * 64;
    const int tid = threadIdx.x;
    #pragma unroll
    for (int kk = 0; kk < 4; ++kk) {
        int l = tid + kk * 256;
        int row = l >> 4, c4 = l & 15;
        const unsigned short* src = vp + ((long long)b * SS + t0 + row) * DM + h * 64 + c4 * 4;
        ushort4 val = *reinterpret_cast<const ushort4*>(src);
        tile[row][c4 * 4 + 0] = val.x;
        tile[row][c4 * 4 + 1] = val.y;
        tile[row][c4 * 4 + 2] = val.z;
        tile[row][c4 * 4 + 3] = val.w;
    }
    __syncthreads();
    #pragma unroll
    for (int kk = 0; kk < 4; ++kk) {
        int l = tid + kk * 256;
        int d = l >> 4, i4 = l & 15;
        ushort4 o;
        o.x = tile[i4 * 4 + 0][d];
        o.y = tile[i4 * 4 + 1][d];
        o.z = tile[i4 * 4 + 2][d];
        o.w = tile[i4 * 4 + 3][d];
        *reinterpret_cast<ushort4*>(vT + ((long long)bh * 64 + d) * SS + t0 + i4 * 4) = o;
    }
}

// Fused attention v3:
//   P1: QK^T (2-deep K-frag prefetch) -> S16 bf16 LDS; lane-local online (m,s)
//   P2: (m,s) group-merge (shuffle) -> cross-wave merge   [round-5 combine]
//   P3: attnw = exp(bf16 S - m) * inv from S16 LDS, coalesced 4KB/row stores
//   P4: PV from S16 -> cc                                  [round-4/5/6 verified]
// Grid: (SS/16, B*NH), 256 threads = 4 waves.  No sreg -> VGPR < 128 -> 4 blocks/CU.
__global__ __launch_bounds__(256, 4) void fused_attn3(
    const unsigned short* __restrict__ qp,   // [B,S,DM] bf16
    const unsigned short* __restrict__ kp,   // [B,S,DM] bf16
    const unsigned short* __restrict__ vT,   // [B*NH*64, S] bf16
    float* __restrict__ attnw,               // [B,NH,S,S] f32
    unsigned short* __restrict__ cc)         // [B,S,DM] bf16
{
    constexpr int LSTR = 1032;
    __shared__ alignas(16) unsigned short S16[16 * LSTR];   // 33 KB
    __shared__ float2 msW[4][16];
    __shared__ float rowM[16];
    __shared__ float rowI[16];

    const int tid = threadIdx.x;
    const int w = tid >> 6;
    const int lane = tid & 63;
    const int lg = lane >> 4;
    const int ln = lane & 15;
    const int z = blockIdx.y, b = z >> 4, h = z & 15;
    const int row0 = blockIdx.x * 16;

    const unsigned short* qbase = qp + ((long long)b * SS + row0) * DM + h * 64;
    const unsigned short* kbase = kp + (long long)b * SS * DM + h * 64;
    const unsigned short* vbase = vT + (long long)z * 64 * SS;

    bf16x8 qf[2];
    #pragma unroll
    for (int ks = 0; ks < 2; ++ks)
        qf[ks] = *reinterpret_cast<const bf16x8*>(qbase + (long long)ln * DM + ks * 32 + lg * 8);

    float m4[4], s4[4];
    #pragma unroll
    for (int j = 0; j < 4; ++j) { m4[j] = -1e30f; s4[j] = 0.f; }

    // ---- Phase 1: QK^T with 2-deep K-fragment prefetch ----
    bf16x8 kf_cur[4];
    #pragma unroll
    for (int i = 0; i < 4; ++i) {
        const int ks = i >> 1, cf2 = i & 1;
        kf_cur[i] = *reinterpret_cast<const bf16x8*>(
            kbase + (long long)(w * 32 + cf2 * 16 + ln) * DM + ks * 32 + lg * 8);
    }
    for (int c = 0; c < 8; ++c) {
        bf16x8 kf_nxt[4];
        if (c < 7) {
            #pragma unroll
            for (int i = 0; i < 4; ++i) {
                const int ks = i >> 1, cf2 = i & 1;
                kf_nxt[i] = *reinterpret_cast<const bf16x8*>(
                    kbase + (long long)((c + 1) * 128 + w * 32 + cf2 * 16 + ln) * DM + ks * 32 + lg * 8);
            }
        }
        f32x4 sac[2];
        sac[0] = f32x4{0.f, 0.f, 0.f, 0.f};
        sac[1] = f32x4{0.f, 0.f, 0.f, 0.f};
        sac[0] = __builtin_amdgcn_mfma_f32_16x16x32_bf16(qf[0], kf_cur[0], sac[0], 0, 0, 0);
        sac[1] = __builtin_amdgcn_mfma_f32_16x16x32_bf16(qf[0], kf_cur[1], sac[1], 0, 0, 0);
        sac[0] = __builtin_amdgcn_mfma_f32_16x16x32_bf16(qf[1], kf_cur[2], sac[0], 0, 0, 0);
        sac[1] = __builtin_amdgcn_mfma_f32_16x16x32_bf16(qf[1], kf_cur[3], sac[1], 0, 0, 0);

        const int colbase = c * 128 + w * 32;
        #pragma unroll
        for (int cf2 = 0; cf2 < 2; ++cf2)
            #pragma unroll
            for (int j = 0; j < 4; ++j) {
                unsigned short ub = f2bf(sac[cf2][j] * 0.125f);
                S16[(lg * 4 + j) * LSTR + colbase + cf2 * 16 + ln] = ub;
                sac[cf2][j] = bf2f(ub);   // bf16-consistent value for stats
            }
        // lane-local online (m,s) update — no shuffles in the loop
        #pragma unroll
        for (int j = 0; j < 4; ++j) {
            float v0 = sac[0][j], v1 = sac[1][j];
            float mn = fmaxf(m4[j], fmaxf(v0, v1));
            s4[j] = s4[j] * __expf(m4[j] - mn) + __expf(v0 - mn) + __expf(v1 - mn);
            m4[j] = mn;
        }
        if (c < 7) {
            #pragma unroll
            for (int i = 0; i < 4; ++i) kf_cur[i] = kf_nxt[i];
        }
    }

    // ---- Phase 2: merge (m,s) within 16-lane group, then across waves ----
    #pragma unroll
    for (int j = 0; j < 4; ++j) {
        #pragma unroll
        for (int o = 1; o < 16; o <<= 1) {
            float mo = __shfl_xor(m4[j], o);
            float so = __shfl_xor(s4[j], o);
            float mn = fmaxf(m4[j], mo);
            s4[j] = s4[j] * __expf(m4[j] - mn) + so * __expf(mo - mn);
            m4[j] = mn;
        }
    }
    if (ln == 0) {
        #pragma unroll
        for (int j = 0; j < 4; ++j) msW[w][lg * 4 + j] = make_float2(m4[j], s4[j]);
    }
    __syncthreads();
    if (tid < 16) {
        float mf = -1e30f;
        #pragma unroll
        for (int w2 = 0; w2 < 4; ++w2) mf = fmaxf(mf, msW[w2][tid].x);
        float sf = 0.f;
        #pragma unroll
        for (int w2 = 0; w2 < 4; ++w2) sf += msW[w2][tid].y * __expf(msW[w2][tid].x - mf);
        rowM[tid] = mf;
        rowI[tid] = 1.0f / sf;
    }
    __syncthreads();

    // ---- Phase 3: attnw from S16 (bf16), coalesced row stores ----
    #pragma unroll 4
    for (int it = 0; it < 16; ++it) {
        float mf = rowM[it], inv = rowI[it];
        uint2 sv = *reinterpret_cast<const uint2*>(&S16[it * LSTR + tid * 4]);
        float4 o;
        o.x = __expf(bf2f((unsigned short)(sv.x & 0xffffu)) - mf) * inv;
        o.y = __expf(bf2f((unsigned short)(sv.x >> 16)) - mf) * inv;
        o.z = __expf(bf2f((unsigned short)(sv.y & 0xffffu)) - mf) * inv;
        o.w = __expf(bf2f((unsigned short)(sv.y >> 16)) - mf) * inv;
        *reinterpret_cast<float4*>(attnw + ((long long)z * SS + row0 + it) * SS + tid * 4) = o;
    }

    // ---- Phase 4: PV, wave w owns d in [w*16, w*16+16)  (verified) ----
    {
        f32x4 pvn = f32x4{0.f, 0.f, 0.f, 0.f};
        const unsigned short* vrow = vbase + (long long)(w * 16 + ln) * SS;
        for (int kk = 0; kk < 32; ++kk) {
            bf16x8 sa = *reinterpret_cast<const bf16x8*>(&S16[ln * LSTR + kk * 32 + lg * 8]);
            bf16x8 vf = *reinterpret_cast<const bf16x8*>(vrow + kk * 32 + lg * 8);
            pvn = __builtin_amdgcn_mfma_f32_16x16x32_bf16(sa, vf, pvn, 0, 0, 0);
        }
        #pragma unroll
        for (int j = 0; j < 4; ++j)
            cc[((long long)b * SS + row0 + lg * 4 + j) * DM + h * 64 + w * 16 + ln] = f2bf(pvn[j]);
    }
}

extern "C" void kernel_launch(void* const* d_in, const int* in_sizes, int n_in,
                              void* d_out, int out_size, void* d_ws, size_t ws_size,
                              hipStream_t stream) {
    (void)in_sizes; (void)n_in; (void)out_size; (void)ws_size;
    const float* v    = (const float*)d_in[0];
    const float* q    = (const float*)d_in[2];
    const float* wq_w = (const float*)d_in[3];
    const float* wq_b = (const float*)d_in[4];
    const float* wv_w = (const float*)d_in[5];
    const float* wv_b = (const float*)d_in[6];
    const float* dw   = (const float*)d_in[7];
    const float* db   = (const float*)d_in[8];

    // workspace: 5 x 4M bf16 = 40 MB
    unsigned short* q_p = (unsigned short*)d_ws;
    unsigned short* v_p = q_p + (4 << 20);
    unsigned short* k_p = v_p + (4 << 20);
    unsigned short* vT  = k_p + (4 << 20);
    unsigned short* cc  = vT  + (4 << 20);

    float* out0   = (float*)d_out;
    float* attnw  = out0 + (long long)BS * SS * DM;

    // bf16 conversion buffers parked in the attnw region (dead until fused_attn3)
    unsigned short* qb  = (unsigned short*)attnw;
    unsigned short* vb  = qb  + (4 << 20);
    unsigned short* wqb = vb  + (4 << 20);
    unsigned short* wvb = wqb + (1 << 20);
    // dwb reuses q_p's slot AFTER fused_attn3 (q_p dead by then)
    unsigned short* dwb = q_p;

    dim3 blk(256);
    dim3 gemmGrid(DM / 64, BS * SS / 64);    // (16, 64)

    cvt_bf16<<<dim3(1024), blk, 0, stream>>>(q, qb, (BS * SS * DM) / 4);
    cvt_bf16<<<dim3(1024), blk, 0, stream>>>(v, vb, (BS * SS * DM) / 4);
    cvt_bf16<<<dim3(256),  blk, 0, stream>>>(wq_w, wqb, (DM * DM) / 4);
    cvt_bf16<<<dim3(256),  blk, 0, stream>>>(wv_w, wvb, (DM * DM) / 4);

    gemm64_bt<unsigned short><<<gemmGrid, blk, 0, stream>>>(
        qb, DM, wqb, DM, q_p, DM, wq_b, DM, 1.0f);
    gemm64_bt<unsigned short><<<gemmGrid, blk, 0, stream>>>(
        vb, DM, wvb, DM, v_p, DM, wv_b, DM, 1.0f);
    gemm64_bt<unsigned short><<<gemmGrid, blk, 0, stream>>>(
        v_p, DM, wvb, DM, k_p, DM, wv_b, DM, 1.0f);

    transpose_vh<<<dim3(16, 64), blk, 0, stream>>>(v_p, vT);

    fused_attn3<<<dim3(SS / 16, BS * NH), blk, 0, stream>>>(q_p, k_p, vT, attnw, cc);

    cvt_bf16<<<dim3(256), blk, 0, stream>>>(dw, dwb, (DM * DM) / 4);
    gemm64_bt<float><<<gemmGrid, blk, 0, stream>>>(
        cc, DM, dwb, DM, out0, DM, db, DM, 1.0f);
}

// Round 9
// 246.043 us; speedup vs baseline: 1.7533x; 1.0132x over previous
//
#include <hip/hip_runtime.h>
#include <hip/hip_bf16.h>

#define DM 1024
#define BS 4
#define SS 1024
#define NH 16

typedef __attribute__((ext_vector_type(8))) short bf16x8;
typedef __attribute__((ext_vector_type(4))) float f32x4;

__device__ inline unsigned short f2bf(float x) {
    union { float f; unsigned u; } v; v.f = x;
    unsigned r = v.u + 0x7fffu + ((v.u >> 16) & 1u);
    return (unsigned short)(r >> 16);
}
__device__ inline float bf2f(unsigned short u) {
    union { unsigned u; float f; } v; v.u = ((unsigned)u) << 16;
    return v.f;
}

template<typename T> __device__ inline void store1(T* p, float v);
template<> __device__ inline void store1<float>(float* p, float v) { *p = v; }
template<> __device__ inline void store1<unsigned short>(unsigned short* p, float v) { *p = f2bf(v); }

// async global->LDS, 16B per lane; LDS dest = wave-uniform base + lane*16
__device__ inline void glds16(const unsigned short* g, unsigned short* l) {
    __builtin_amdgcn_global_load_lds(
        (const __attribute__((address_space(1))) unsigned int*)g,
        (__attribute__((address_space(3))) unsigned int*)l, 16, 0, 0);
}

// fp32 -> bf16 elementwise, float4/ushort4 vectorized, grid-stride
__global__ __launch_bounds__(256) void cvt_bf16(const float* __restrict__ in,
                                                unsigned short* __restrict__ out, int n4)
{
    int i = blockIdx.x * blockDim.x + threadIdx.x;
    const int stride = gridDim.x * blockDim.x;
    for (; i < n4; i += stride) {
        float4 v = reinterpret_cast<const float4*>(in)[i];
        ushort4 o;
        o.x = f2bf(v.x); o.y = f2bf(v.y); o.z = f2bf(v.z); o.w = f2bf(v.w);
        reinterpret_cast<ushort4*>(out)[i] = o;
    }
}

// C[M,N] = scale*(A[M,K] @ B[N,K]^T) + bias[N], all-bf16, glds16 staging,
// 2-phase dbuf pipeline (round-8 verified structure), BM=128 BN=64 BK=32,
// 4 waves (2x2 of 64x32 tiles). Grid: (N/64, M/128).
template<typename TO>
__global__ __launch_bounds__(256) void gemm128_bt(
    const unsigned short* __restrict__ A, int lda,
    const unsigned short* __restrict__ B, int ldb,
    TO* __restrict__ C, int ldc,
    const float* __restrict__ bias, int K, float scale)
{
    __shared__ unsigned short lA[2][128 * 32];   // 8KB x2
    __shared__ unsigned short lB[2][64 * 32];    // 4KB x2

    const int tid = threadIdx.x;
    const int wid = tid >> 6, lane = tid & 63;
    const int wr = wid >> 1, wc = wid & 1;
    const int r0 = lane & 15;
    const int kq = (lane >> 4) * 8;
    const int srow = lane >> 2;          // 16 rows per wave-glds16
    const int scol = (lane & 3) * 8;     // 4 lanes x 16B = 64B row

    const unsigned short* Ap = A + ((long long)blockIdx.y * 128 + srow) * lda + scol;
    const unsigned short* Bp = B + ((long long)blockIdx.x * 64 + srow) * ldb + scol;
    TO* Cp = C + (long long)blockIdx.y * 128 * ldc + blockIdx.x * 64;

    f32x4 acc[4][2];
    #pragma unroll
    for (int m = 0; m < 4; ++m)
        #pragma unroll
        for (int n = 0; n < 2; ++n)
            acc[m][n] = f32x4{0.f, 0.f, 0.f, 0.f};

    // prologue: stage tile 0 (wave wid: A rows [wid*32, wid*32+32), B rows [wid*16,..))
    glds16(Ap + (long long)(wid * 32) * lda, &lA[0][wid * 1024]);
    glds16(Ap + (long long)(wid * 32 + 16) * lda, &lA[0][wid * 1024 + 512]);
    glds16(Bp + (long long)(wid * 16) * ldb, &lB[0][wid * 512]);
    __syncthreads();

    const int NT = K / 32;
    int cur = 0;
    for (int t = 0; t < NT; ++t) {
        if (t + 1 < NT) {
            glds16(Ap + (long long)(wid * 32) * lda + (t + 1) * 32, &lA[cur ^ 1][wid * 1024]);
            glds16(Ap + (long long)(wid * 32 + 16) * lda + (t + 1) * 32, &lA[cur ^ 1][wid * 1024 + 512]);
            glds16(Bp + (long long)(wid * 16) * ldb + (t + 1) * 32, &lB[cur ^ 1][wid * 512]);
        }
        bf16x8 af[4], bfr[2];
        #pragma unroll
        for (int m = 0; m < 4; ++m)
            af[m] = *reinterpret_cast<const bf16x8*>(&lA[cur][(wr * 64 + m * 16 + r0) * 32 + kq]);
        #pragma unroll
        for (int n = 0; n < 2; ++n)
            bfr[n] = *reinterpret_cast<const bf16x8*>(&lB[cur][(wc * 32 + n * 16 + r0) * 32 + kq]);
        #pragma unroll
        for (int m = 0; m < 4; ++m)
            #pragma unroll
            for (int n = 0; n < 2; ++n)
                acc[m][n] = __builtin_amdgcn_mfma_f32_16x16x32_bf16(af[m], bfr[n], acc[m][n], 0, 0, 0);
        __syncthreads();
        cur ^= 1;
    }

    const int cf = lane & 15, rf = (lane >> 4) * 4;
    #pragma unroll
    for (int m = 0; m < 4; ++m) {
        #pragma unroll
        for (int n = 0; n < 2; ++n) {
            int col = wc * 32 + n * 16 + cf;
            float bv = bias ? bias[blockIdx.x * 64 + col] : 0.0f;
            #pragma unroll
            for (int j = 0; j < 4; ++j) {
                int row = wr * 64 + m * 16 + rf + j;
                store1<TO>(&Cp[(long long)row * ldc + col], acc[m][n][j] * scale + bv);
            }
        }
    }
}

// vT[(b*NH+h)*64 + d][t] = v_p[b][t][h*64+d]   (round-1 verified)
__global__ __launch_bounds__(256) void transpose_vh(const unsigned short* __restrict__ vp,
                                                    unsigned short* __restrict__ vT)
{
    __shared__ unsigned short tile[64][65];
    const int bh = blockIdx.y;
    const int b = bh >> 4, h = bh & 15;
    const long long t0 = (long long)blockIdx.x * 64;
    const int tid = threadIdx.x;
    #pragma unroll
    for (int kk = 0; kk < 4; ++kk) {
        int l = tid + kk * 256;
        int row = l >> 4, c4 = l & 15;
        const unsigned short* src = vp + ((long long)b * SS + t0 + row) * DM + h * 64 + c4 * 4;
        ushort4 val = *reinterpret_cast<const ushort4*>(src);
        tile[row][c4 * 4 + 0] = val.x;
        tile[row][c4 * 4 + 1] = val.y;
        tile[row][c4 * 4 + 2] = val.z;
        tile[row][c4 * 4 + 3] = val.w;
    }
    __syncthreads();
    #pragma unroll
    for (int kk = 0; kk < 4; ++kk) {
        int l = tid + kk * 256;
        int d = l >> 4, i4 = l & 15;
        ushort4 o;
        o.x = tile[i4 * 4 + 0][d];
        o.y = tile[i4 * 4 + 1][d];
        o.z = tile[i4 * 4 + 2][d];
        o.w = tile[i4 * 4 + 3][d];
        *reinterpret_cast<ushort4*>(vT + ((long long)bh * 64 + d) * SS + t0 + i4 * 4) = o;
    }
}

// Fused attention v4: QBLK=32, 512 threads (8 waves). K-fragments shared across
// two q-row-halves (halves K gather traffic vs v3). Phases as round-8 verified:
//   P1: QK^T (2-deep kf prefetch, shared kf, 2 row-halves) -> S16 bf16 LDS;
//       lane-local online (m,s) on bf16-consistent values
//   P2: shuffle merge over 16 cols-lanes, then 8-wave LDS merge
//   P3: attnw = exp(bf16 S - m)*inv from S16, coalesced float4 stores
//   P4: PV from S16 -> cc (wave w: row-half w>>2, d-slice w&3)
// Grid: (SS/32, B*NH).
__global__ __launch_bounds__(512, 4) void fused_attn4(
    const unsigned short* __restrict__ qp,   // [B,S,DM] bf16
    const unsigned short* __restrict__ kp,   // [B,S,DM] bf16
    const unsigned short* __restrict__ vT,   // [B*NH*64, S] bf16
    float* __restrict__ attnw,               // [B,NH,S,S] f32
    unsigned short* __restrict__ cc)         // [B,S,DM] bf16
{
    constexpr int LSTR = 1032;
    __shared__ alignas(16) unsigned short S16[32 * LSTR];   // 66 KB
    __shared__ float2 msW[8][32];
    __shared__ float rowM[32];
    __shared__ float rowI[32];

    const int tid = threadIdx.x;
    const int w = tid >> 6;                  // 0..7
    const int lane = tid & 63;
    const int lg = lane >> 4;                // 0..3
    const int ln = lane & 15;                // 0..15
    const int z = blockIdx.y, b = z >> 4, h = z & 15;
    const int row0 = blockIdx.x * 32;

    const unsigned short* qbase = qp + ((long long)b * SS + row0) * DM + h * 64;
    const unsigned short* kbase = kp + (long long)b * SS * DM + h * 64;
    const unsigned short* vbase = vT + (long long)z * 64 * SS;

    // Q fragments for both row-halves
    bf16x8 qf[2][2];                         // [rh][ks]
    #pragma unroll
    for (int rh = 0; rh < 2; ++rh)
        #pragma unroll
        for (int ks = 0; ks < 2; ++ks)
            qf[rh][ks] = *reinterpret_cast<const bf16x8*>(
                qbase + (long long)(rh * 16 + ln) * DM + ks * 32 + lg * 8);

    float m4[2][4], s4[2][4];
    #pragma unroll
    for (int rh = 0; rh < 2; ++rh)
        #pragma unroll
        for (int j = 0; j < 4; ++j) { m4[rh][j] = -1e30f; s4[rh][j] = 0.f; }

    // ---- Phase 1: QK^T, 4 chunks of 256 cols, wave owns 32 cols/chunk ----
    bf16x8 kf_cur[4];                        // [ks*2+cf]
    #pragma unroll
    for (int i = 0; i < 4; ++i) {
        const int ks = i >> 1, cf2 = i & 1;
        kf_cur[i] = *reinterpret_cast<const bf16x8*>(
            kbase + (long long)(w * 32 + cf2 * 16 + ln) * DM + ks * 32 + lg * 8);
    }
    for (int c = 0; c < 4; ++c) {
        bf16x8 kf_nxt[4];
        if (c < 3) {
            #pragma unroll
            for (int i = 0; i < 4; ++i) {
                const int ks = i >> 1, cf2 = i & 1;
                kf_nxt[i] = *reinterpret_cast<const bf16x8*>(
                    kbase + (long long)((c + 1) * 256 + w * 32 + cf2 * 16 + ln) * DM + ks * 32 + lg * 8);
            }
        }
        f32x4 sac[2][2];                     // [rh][cf]
        #pragma unroll
        for (int rh = 0; rh < 2; ++rh) {
            sac[rh][0] = f32x4{0.f, 0.f, 0.f, 0.f};
            sac[rh][1] = f32x4{0.f, 0.f, 0.f, 0.f};
        }
        #pragma unroll
        for (int ks = 0; ks < 2; ++ks)
            #pragma unroll
            for (int cf2 = 0; cf2 < 2; ++cf2)
                #pragma unroll
                for (int rh = 0; rh < 2; ++rh)
                    sac[rh][cf2] = __builtin_amdgcn_mfma_f32_16x16x32_bf16(
                        qf[rh][ks], kf_cur[ks * 2 + cf2], sac[rh][cf2], 0, 0, 0);

        const int colbase = c * 256 + w * 32;
        #pragma unroll
        for (int rh = 0; rh < 2; ++rh) {
            #pragma unroll
            for (int cf2 = 0; cf2 < 2; ++cf2)
                #pragma unroll
                for (int j = 0; j < 4; ++j) {
                    unsigned short ub = f2bf(sac[rh][cf2][j] * 0.125f);
                    S16[(rh * 16 + lg * 4 + j) * LSTR + colbase + cf2 * 16 + ln] = ub;
                    sac[rh][cf2][j] = bf2f(ub);
                }
            #pragma unroll
            for (int j = 0; j < 4; ++j) {
                float v0 = sac[rh][0][j], v1 = sac[rh][1][j];
                float mn = fmaxf(m4[rh][j], fmaxf(v0, v1));
                s4[rh][j] = s4[rh][j] * __expf(m4[rh][j] - mn) + __expf(v0 - mn) + __expf(v1 - mn);
                m4[rh][j] = mn;
            }
        }
        if (c < 3) {
            #pragma unroll
            for (int i = 0; i < 4; ++i) kf_cur[i] = kf_nxt[i];
        }
    }

    // ---- Phase 2: merge within 16-lane col group, then across 8 waves ----
    #pragma unroll
    for (int rh = 0; rh < 2; ++rh)
        #pragma unroll
        for (int j = 0; j < 4; ++j) {
            #pragma unroll
            for (int o = 1; o < 16; o <<= 1) {
                float mo = __shfl_xor(m4[rh][j], o);
                float so = __shfl_xor(s4[rh][j], o);
                float mn = fmaxf(m4[rh][j], mo);
                s4[rh][j] = s4[rh][j] * __expf(m4[rh][j] - mn) + so * __expf(mo - mn);
                m4[rh][j] = mn;
            }
        }
    if (ln == 0) {
        #pragma unroll
        for (int rh = 0; rh < 2; ++rh)
            #pragma unroll
            for (int j = 0; j < 4; ++j)
                msW[w][rh * 16 + lg * 4 + j] = make_float2(m4[rh][j], s4[rh][j]);
    }
    __syncthreads();
    if (tid < 32) {
        float mf = -1e30f;
        #pragma unroll
        for (int w2 = 0; w2 < 8; ++w2) mf = fmaxf(mf, msW[w2][tid].x);
        float sf = 0.f;
        #pragma unroll
        for (int w2 = 0; w2 < 8; ++w2) sf += msW[w2][tid].y * __expf(msW[w2][tid].x - mf);
        rowM[tid] = mf;
        rowI[tid] = 1.0f / sf;
    }
    __syncthreads();

    // ---- Phase 3: attnw from S16 (bf16), 2 rows per iteration ----
    {
        const int rr = tid >> 8;             // 0..1
        const int tcol = tid & 255;
        #pragma unroll 4
        for (int it = 0; it < 16; ++it) {
            const int row = it * 2 + rr;
            float mf = rowM[row], inv = rowI[row];
            uint2 sv = *reinterpret_cast<const uint2*>(&S16[row * LSTR + tcol * 4]);
            float4 o;
            o.x = __expf(bf2f((unsigned short)(sv.x & 0xffffu)) - mf) * inv;
            o.y = __expf(bf2f((unsigned short)(sv.x >> 16)) - mf) * inv;
            o.z = __expf(bf2f((unsigned short)(sv.y & 0xffffu)) - mf) * inv;
            o.w = __expf(bf2f((unsigned short)(sv.y >> 16)) - mf) * inv;
            *reinterpret_cast<float4*>(attnw + ((long long)z * SS + row0 + row) * SS + tcol * 4) = o;
        }
    }

    // ---- Phase 4: PV, wave w: row-half rh=w>>2, d-slice ds=w&3 ----
    {
        const int rh = w >> 2, ds = w & 3;
        f32x4 pvn = f32x4{0.f, 0.f, 0.f, 0.f};
        const unsigned short* vrow = vbase + (long long)(ds * 16 + ln) * SS;
        for (int kk = 0; kk < 32; ++kk) {
            bf16x8 sa = *reinterpret_cast<const bf16x8*>(&S16[(rh * 16 + ln) * LSTR + kk * 32 + lg * 8]);
            bf16x8 vf = *reinterpret_cast<const bf16x8*>(vrow + kk * 32 + lg * 8);
            pvn = __builtin_amdgcn_mfma_f32_16x16x32_bf16(sa, vf, pvn, 0, 0, 0);
        }
        #pragma unroll
        for (int j = 0; j < 4; ++j)
            cc[((long long)b * SS + row0 + rh * 16 + lg * 4 + j) * DM + h * 64 + ds * 16 + ln] = f2bf(pvn[j]);
    }
}

extern "C" void kernel_launch(void* const* d_in, const int* in_sizes, int n_in,
                              void* d_out, int out_size, void* d_ws, size_t ws_size,
                              hipStream_t stream) {
    (void)in_sizes; (void)n_in; (void)out_size; (void)ws_size;
    const float* v    = (const float*)d_in[0];
    const float* q    = (const float*)d_in[2];
    const float* wq_w = (const float*)d_in[3];
    const float* wq_b = (const float*)d_in[4];
    const float* wv_w = (const float*)d_in[5];
    const float* wv_b = (const float*)d_in[6];
    const float* dw   = (const float*)d_in[7];
    const float* db   = (const float*)d_in[8];

    // workspace: 5 x 4M bf16 = 40 MB
    unsigned short* q_p = (unsigned short*)d_ws;
    unsigned short* v_p = q_p + (4 << 20);
    unsigned short* k_p = v_p + (4 << 20);
    unsigned short* vT  = k_p + (4 << 20);
    unsigned short* cc  = vT  + (4 << 20);

    float* out0   = (float*)d_out;
    float* attnw  = out0 + (long long)BS * SS * DM;

    // bf16 conversion buffers parked in the attnw region (dead until fused_attn4)
    unsigned short* qb  = (unsigned short*)attnw;
    unsigned short* vb  = qb  + (4 << 20);
    unsigned short* wqb = vb  + (4 << 20);
    unsigned short* wvb = wqb + (1 << 20);
    // dwb reuses q_p's slot AFTER fused_attn4 (q_p dead by then)
    unsigned short* dwb = q_p;

    dim3 blk(256);
    dim3 gemmGrid(DM / 64, BS * SS / 128);   // (16, 32)

    cvt_bf16<<<dim3(1024), blk, 0, stream>>>(q, qb, (BS * SS * DM) / 4);
    cvt_bf16<<<dim3(1024), blk, 0, stream>>>(v, vb, (BS * SS * DM) / 4);
    cvt_bf16<<<dim3(256),  blk, 0, stream>>>(wq_w, wqb, (DM * DM) / 4);
    cvt_bf16<<<dim3(256),  blk, 0, stream>>>(wv_w, wvb, (DM * DM) / 4);

    gemm128_bt<unsigned short><<<gemmGrid, blk, 0, stream>>>(
        qb, DM, wqb, DM, q_p, DM, wq_b, DM, 1.0f);
    gemm128_bt<unsigned short><<<gemmGrid, blk, 0, stream>>>(
        vb, DM, wvb, DM, v_p, DM, wv_b, DM, 1.0f);
    gemm128_bt<unsigned short><<<gemmGrid, blk, 0, stream>>>(
        v_p, DM, wvb, DM, k_p, DM, wv_b, DM, 1.0f);

    transpose_vh<<<dim3(16, 64), blk, 0, stream>>>(v_p, vT);

    fused_attn4<<<dim3(SS / 32, BS * NH), dim3(512), 0, stream>>>(q_p, k_p, vT, attnw, cc);

    cvt_bf16<<<dim3(256), blk, 0, stream>>>(dw, dwb, (DM * DM) / 4);
    gemm128_bt<float><<<gemmGrid, blk, 0, stream>>>(
        cc, DM, dwb, DM, out0, DM, db, DM, 1.0f);
}